// Round 26
// baseline (90.386 us; speedup 1.0000x reference)
//
#include <hip/hip_runtime.h>

typedef int   v8i    __attribute__((ext_vector_type(8)));
typedef float f32x16 __attribute__((ext_vector_type(16)));

#define NI 256
#define NT 256
#define NL 32
#define NE 128
#define HW 49
#define NEG_INF (-3.0e38f)
#define SCALE1 0x7F7F7F7F   // e8m0 = 127 -> x1.0, all blocks

// Fragment layouts (identical math to R15-R24, now built in-block):
//  A frag fi = mt*2+ks: byte j of lane l
//      = img[i, e=ks*64+(l>>5)*32+j, hw=min(mt*32+(l&31),48)]
//  B (split-16B) text t, ks: lane l bytes 0-15 at t*4096+ks*2048+l*16,
//      bytes 16-31 at +1024; byte j = txt[t, l&31, e=ks*64+(l>>5)*32+j]
//  A and B share the k<->(lane,byte) map -> k-permutation cancels.

__device__ __forceinline__ unsigned char f32_to_e4m3(float f)
{
    unsigned fb = __float_as_uint(f);
    unsigned s  = (fb >> 24) & 0x80;
    int      e  = (int)((fb >> 23) & 0xFF);
    unsigned m  = fb & 0x7FFFFF;
    int ne = e - 120;
    if (ne <= 0)  return (unsigned char)s;
    if (ne > 15) { ne = 15; m = 0x600000; }
    unsigned base = ((unsigned)ne << 3) | (m >> 20);
    unsigned rem  = m & 0xFFFFF;
    if (rem > 0x80000 || (rem == 0x80000 && (base & 1))) base++;   // RNE
    if (base > 0x7E) base = 0x7E;
    return (unsigned char)(s | base);
}

// ---------- single fused kernel, ZERO grid barriers ----------
// Grid 1024 = 16 tb x 64 ig, bid = tb*64 + ig: all 16 sharers of ig are on
// ONE XCD (bid%8 == ig%8) -> image re-reads hit home L2 (no R20 blowup).
// Each block: [A-phase: 4x {coop-load img -> LDS, gather+cvt -> fp8, owner
// wave -> regs}] [2x {cvt 8 texts -> bstage LDS, compute}]. Cold input
// reads overlap MFMA across de-phased blocks - no prep dispatch, no gap.
__global__ __launch_bounds__(256, 4)
void clip_fused_kernel(const float* __restrict__ img,
                       const float* __restrict__ txt,
                       const int* __restrict__ tlen,
                       const float* __restrict__ nlt,
                       float* __restrict__ out)
{
    const int tid  = threadIdx.x;
    const int wave = tid >> 6, lane = tid & 63;
    const int ml   = lane & 31, h = lane >> 5;
    const int bid  = blockIdx.x;
    const int tb   = bid >> 6;           // text chunk (16 texts)
    const int ig   = bid & 63;           // image group (4 images)
    const int im   = ig * 4 + wave;      // this wave's image

    __shared__ __align__(16) unsigned char lds_all[40960];
    // A-phase:   scratch fp32 [0,25088) + Aout fp8 [25600,33792)
    // compute:   bstage [0,32768) + colmax [32768,40960)
    float*         scratch = (float*)lds_all;
    unsigned char* Aout    = lds_all + 25600;
    unsigned char* bstage  = lds_all;
    float (*colmax)[16][32] = (float(*)[16][32])(lds_all + 32768);

    // ================= A-phase: own images -> fragment regs =================
    v8i aA0, aA1, aB0, aB1;
    #pragma unroll
    for (int r4 = 0; r4 < 4; ++r4) {
        const int p     = (r4 + (tb & 3)) & 3;     // stagger sharers of ig
        const int image = ig * 4 + p;
        // coop-load image p (25088 B = 1568 float4), coalesced
        const float4* src4 = (const float4*)(img + (size_t)image * (NE * HW));
        #pragma unroll
        for (int q = 0; q < 7; ++q) {
            int idx = tid + 256 * q;
            if (idx < 1568) ((float4*)scratch)[idx] = src4[idx];
        }
        __syncthreads();                           // scratch ready
        // gather+cvt: thread = (frag fi, lane l); conflict-free-ish reads
        {
            int fi = tid >> 6, l = tid & 63;
            int mt = fi >> 1, ksg = fi & 1;
            int m  = mt * 32 + (l & 31); if (m > HW - 1) m = HW - 1;
            int e0 = ksg * 64 + (l >> 5) * 32;
            union { unsigned char b[32]; int4 v[2]; } ug;
            #pragma unroll
            for (int j = 0; j < 32; ++j)
                ug.b[j] = f32_to_e4m3(scratch[(e0 + j) * HW + m]);
            *(int4*)(Aout + fi * 2048 + l * 32)      = ug.v[0];
            *(int4*)(Aout + fi * 2048 + l * 32 + 16) = ug.v[1];
        }
        __syncthreads();                           // Aout ready
        if (wave == p) {                           // owner copies to regs
            const unsigned char* pa = Aout + lane * 32;
            aA0 = *(const v8i*)(pa);               // mt0 ks0
            aA1 = *(const v8i*)(pa + 2048);        // mt0 ks1
            aB0 = *(const v8i*)(pa + 4096);        // mt1 ks0
            aB1 = *(const v8i*)(pa + 6144);        // mt1 ks1
        }
    }
    __syncthreads();   // all waves own their regs; LDS free for bstage

#define COMPUTE(bk0, bk1, t)                                                \
    {                                                                       \
        f32x16 acc0 = __builtin_amdgcn_mfma_scale_f32_32x32x64_f8f6f4(      \
            aA0, bk0, (f32x16)(0.f), 0, 0, 0, SCALE1, 0, SCALE1);           \
        acc0 = __builtin_amdgcn_mfma_scale_f32_32x32x64_f8f6f4(             \
            aA1, bk1, acc0, 0, 0, 0, SCALE1, 0, SCALE1);                    \
        f32x16 acc1 = __builtin_amdgcn_mfma_scale_f32_32x32x64_f8f6f4(      \
            aB0, bk0, (f32x16)(0.f), 0, 0, 0, SCALE1, 0, SCALE1);           \
        acc1 = __builtin_amdgcn_mfma_scale_f32_32x32x64_f8f6f4(             \
            aB1, bk1, acc1, 0, 0, 0, SCALE1, 0, SCALE1);                    \
        /* C/D: col=lane&31, row r2=(reg&3)+8*(reg>>2)+4*h; acc0: m=r2     \
           (all 16 valid); acc1: m=32+r2 -> regs 0..7, +reg8 iff h==0 */   \
        float t0[8];                                                        \
        _Pragma("unroll")                                                   \
        for (int k = 0; k < 8; ++k) t0[k] = fmaxf(acc0[2*k], acc0[2*k+1]);  \
        float t1[4];                                                        \
        _Pragma("unroll")                                                   \
        for (int k = 0; k < 4; ++k) t1[k] = fmaxf(t0[2*k], t0[2*k+1]);      \
        float a0m = fmaxf(fmaxf(t1[0], t1[1]), fmaxf(t1[2], t1[3]));        \
        float u0[4];                                                        \
        _Pragma("unroll")                                                   \
        for (int k = 0; k < 4; ++k) u0[k] = fmaxf(acc1[2*k], acc1[2*k+1]);  \
        float a1m = fmaxf(fmaxf(u0[0], u0[1]), fmaxf(u0[2], u0[3]));        \
        float ex  = (h == 0) ? acc1[8] : NEG_INF;                           \
        float cm  = fmaxf(fmaxf(a0m, a1m), ex);                             \
        cm = fmaxf(cm, __shfl_xor(cm, 32));        /* merge h-halves */     \
        if (h == 0) colmax[wave][t][ml] = cm;                               \
    }

    // ================= B-phase + compute: two halves of 8 texts =============
    #pragma unroll 1
    for (int r = 0; r < 2; ++r) {
        // cvt 8 texts -> bstage (split-16B); 1024 slots, 4 per thread;
        // rotate t_loc per ig to stagger cross-XCD first-touch of txt
        #pragma unroll
        for (int q = 0; q < 4; ++q) {
            int s     = tid + 256 * q;                 // 0..1023
            int t_loc = (((s >> 7) + ig) & 7);
            int rest  = s & 127;
            int ksb   = rest >> 6;
            int l     = rest & 63;
            int t     = tb * 16 + r * 8 + t_loc;
            const float* pb = txt + ((size_t)t * NL + (l & 31)) * NE
                                  + ksb * 64 + (l >> 5) * 32;
            union { unsigned char b[32]; int4 v[2]; } ub;
            #pragma unroll
            for (int w = 0; w < 8; ++w) {
                float4 f = *(const float4*)(pb + w * 4);
                ub.b[w*4+0] = f32_to_e4m3(f.x); ub.b[w*4+1] = f32_to_e4m3(f.y);
                ub.b[w*4+2] = f32_to_e4m3(f.z); ub.b[w*4+3] = f32_to_e4m3(f.w);
            }
            unsigned char* dst = bstage + t_loc * 4096 + ksb * 2048;
            *(int4*)(dst + l * 16)        = ub.v[0];
            *(int4*)(dst + 1024 + l * 16) = ub.v[1];
        }
        __syncthreads();

        // compute 8 texts (conflict-free split-16B ds_read_b128)
        #pragma unroll
        for (int ts = 0; ts < 8; ++ts) {
            const int t = r * 8 + ts;
            union { int4 q[2]; v8i v; } b0, b1;
            const unsigned char* base = bstage + ts * 4096 + lane * 16;
            b0.q[0] = *(const int4*)(base);               // k0 lo
            b0.q[1] = *(const int4*)(base + 1024);        // k0 hi
            b1.q[0] = *(const int4*)(base + 2048);        // k1 lo
            b1.q[1] = *(const int4*)(base + 3072);        // k1 hi
            COMPUTE(b0.v, b1.v, t)
        }
        __syncthreads();   // all waves done with bstage before re-cvt
    }
#undef COMPUTE

    // ---- epilogue: sum 32 cols per text; write both mirrors ----
    {
        const float scale = expf(nlt[0]);
        const int t = lane & 15;             // text within chunk
        const int q = lane >> 4;             // col octet 0..3
        const float* row = &colmax[wave][t][q * 8];
        float4 a0 = *(const float4*)(row + 0);
        float4 a1 = *(const float4*)(row + 4);
        float s = ((a0.x + a0.y) + (a0.z + a0.w))
                + ((a1.x + a1.y) + (a1.z + a1.w));
        s += __shfl_xor(s, 16);
        s += __shfl_xor(s, 32);              // all 32 cols
        if (q == 0) {
            int tg = tb * 16 + t;
            float v = s * scale / (float)tlen[tg];
            out[im * NT + tg] = v;              // logits_per_image[i,t]
            out[NI * NT + tg * NI + im] = v;    // logits_per_text[t,i]
        }
    }
}

extern "C" void kernel_launch(void* const* d_in, const int* in_sizes, int n_in,
                              void* d_out, int out_size, void* d_ws, size_t ws_size,
                              hipStream_t stream)
{
    const float* img  = (const float*)d_in[0];
    const float* txt  = (const float*)d_in[1];
    const int*   tlen = (const int*)d_in[2];
    const float* nlt  = (const float*)d_in[3];
    float* out = (float*)d_out;

    clip_fused_kernel<<<dim3(1024), dim3(256), 0, stream>>>(
        img, txt, tlen, nlt, out);
}

// Round 28
// 29.006 us; speedup vs baseline: 3.1161x; 3.1161x over previous
//
#include <hip/hip_runtime.h>

typedef int   v8i    __attribute__((ext_vector_type(8)));
typedef float f32x16 __attribute__((ext_vector_type(16)));
typedef float f32x4v __attribute__((ext_vector_type(4)));   // for nontemporal

#define NI 256
#define NT 256
#define NL 32
#define NE 128
#define HW 49
#define NEG_INF (-3.0e38f)
#define SCALE1 0x7F7F7F7F   // e8m0 = 127 -> x1.0, all blocks

// ws layout (fp8 e4m3, 32x32x64 fragment-linear), validated R15-R24:
//  wsA: frag gw=(i*2+mt)*2+ks = i*4+fi; lane l holds 32B at gw*2048+l*32
//       byte j = img[i, e=ks*64+(l>>5)*32+j, hw=min(mt*32+(l&31),48)]  (2 MB)
//  wsB (SPLIT-16B): frag gw=t*2+ks; lane l bytes 0-15 at gw*2048+l*16,
//       bytes 16-31 at gw*2048+1024+l*16
//       byte j = txt[t, l&31, e=ks*64+(l>>5)*32+j]                     (1 MB)
//  A and B use the SAME k<->(lane,byte) map -> k-permutation cancels.

__device__ __forceinline__ unsigned char f32_to_e4m3(float f)
{
    unsigned fb = __float_as_uint(f);
    unsigned s  = (fb >> 24) & 0x80;
    int      e  = (int)((fb >> 23) & 0xFF);
    unsigned m  = fb & 0x7FFFFF;
    int ne = e - 120;
    if (ne <= 0)  return (unsigned char)s;
    if (ne > 15) { ne = 15; m = 0x600000; }
    unsigned base = ((unsigned)ne << 3) | (m >> 20);
    unsigned rem  = m & 0xFFFFF;
    if (rem > 0x80000 || (rem == 0x80000 && (base & 1))) base++;   // RNE
    if (base > 0x7E) base = 0x7E;
    return (unsigned char)(s | base);
}

// ---------- pre-kernel v3: cold-read-optimized ----------
// prep_cold ~14us (R25 differential) = first-touch of img/txt vs dirty L3
// + A's strided dword gathers (2x over-fetch, 32B/lane MLP). Fix: A reads
// LINEARLY (nontemporal ext-vector float4: no allocate -> no dirty-evict)
// into LDS, transpose+cvt from LDS (R26-verified formulas). One image per
// block. B: one text per block, nontemporal loads, R24 output formulas.
__global__ __launch_bounds__(256, 2)
void prep_kernel(const float* __restrict__ img,
                 const float* __restrict__ txt,
                 unsigned char* __restrict__ wsA,
                 unsigned char* __restrict__ wsB)
{
    const int tid = threadIdx.x;
    const int bid = blockIdx.x;

    if (bid < 256) {                         // ---- A: image bid ----
        __shared__ __align__(16) float scratch[NE * HW];   // 25088 B
        const int i = bid;
        const f32x4v* src4 = (const f32x4v*)(img + (size_t)i * (NE * HW));
        #pragma unroll
        for (int q = 0; q < 7; ++q) {
            int idx = tid + 256 * q;
            if (idx < (NE * HW) / 4)
                ((f32x4v*)scratch)[idx] = __builtin_nontemporal_load(src4 + idx);
        }
        __syncthreads();
        // transpose + cvt: thread = (frag fi, lane l)  [R26-verified]
        const int fi = tid >> 6, l = tid & 63;
        const int mt = fi >> 1, ks = fi & 1;
        int m  = mt * 32 + (l & 31); if (m > HW - 1) m = HW - 1;
        const int e0 = ks * 64 + (l >> 5) * 32;
        union { unsigned char b[32]; int4 v[2]; } u;
        #pragma unroll
        for (int j = 0; j < 32; ++j)
            u.b[j] = f32_to_e4m3(scratch[(e0 + j) * HW + m]);
        unsigned char* dst = wsA + (size_t)(i * 4 + fi) * 2048 + l * 32;
        *(int4*)(dst)      = u.v[0];
        *(int4*)(dst + 16) = u.v[1];
    } else {                                 // ---- B: text bid-256 ----
        const int t   = bid - 256;
        const int ks  = tid >> 7;            // 0..1
        const int rem = tid & 127;
        const int eh  = rem >> 6;            // 16B half
        const int l   = rem & 63;
        const int e0  = ks * 64 + (l >> 5) * 32 + eh * 16;
        const float* p = txt + ((size_t)t * NL + (l & 31)) * NE + e0;
        union { unsigned char b[16]; int4 v; } u;
        #pragma unroll
        for (int q = 0; q < 4; ++q) {
            f32x4v f = __builtin_nontemporal_load((const f32x4v*)(p + q * 4));
            u.b[q*4+0] = f32_to_e4m3(f.x); u.b[q*4+1] = f32_to_e4m3(f.y);
            u.b[q*4+2] = f32_to_e4m3(f.z); u.b[q*4+3] = f32_to_e4m3(f.w);
        }
        *(int4*)(wsB + (size_t)(t * 2 + ks) * 2048 + eh * 1024 + l * 16) = u.v;
    }
}

#define GLDS(gp, lp) __builtin_amdgcn_global_load_lds(                     \
        (const __attribute__((address_space(1))) void*)(gp),               \
        (__attribute__((address_space(3))) void*)(lp), 16, 0, 0)

// ---------- main kernel: B staged in LDS (R24 exact, best = 27.4us) ----------
__global__ __launch_bounds__(256, 4)
void clip_match_kernel(const unsigned char* __restrict__ wsA,
                       const unsigned char* __restrict__ wsB,
                       const int* __restrict__ tlen,
                       const float* __restrict__ nlt,
                       float* __restrict__ out)
{
    const int tid  = threadIdx.x;
    const int wave = tid >> 6, lane = tid & 63;
    const int ml   = lane & 31, h = lane >> 5;
    const int tb   = blockIdx.x & 15;    // text chunk (16 texts)
    const int ig   = blockIdx.x >> 4;    // image group (4 images)
    const int im   = ig * 4 + wave;      // this wave's image

    __shared__ __align__(16) unsigned char bstage[32768];   // 8 texts
    __shared__ __align__(16) float colmax[4][16][32];       // 8 KB
    // total LDS = 40960 B exactly -> 4 blocks/CU

    const unsigned char* pa = wsA + (size_t)im * 8192 + lane * 32;
    v8i aA0 = *(const v8i*)(pa);            // mt0 ks0
    v8i aA1 = *(const v8i*)(pa + 2048);     // mt0 ks1
    v8i aB0 = *(const v8i*)(pa + 4096);     // mt1 ks0
    v8i aB1 = *(const v8i*)(pa + 6144);     // mt1 ks1

    const unsigned char* csrc = wsB + (size_t)tb * 16 * 4096;   // chunk base

#define COMPUTE(bk0, bk1, t)                                                \
    {                                                                       \
        f32x16 acc0 = __builtin_amdgcn_mfma_scale_f32_32x32x64_f8f6f4(      \
            aA0, bk0, (f32x16)(0.f), 0, 0, 0, SCALE1, 0, SCALE1);           \
        acc0 = __builtin_amdgcn_mfma_scale_f32_32x32x64_f8f6f4(             \
            aA1, bk1, acc0, 0, 0, 0, SCALE1, 0, SCALE1);                    \
        f32x16 acc1 = __builtin_amdgcn_mfma_scale_f32_32x32x64_f8f6f4(      \
            aB0, bk0, (f32x16)(0.f), 0, 0, 0, SCALE1, 0, SCALE1);           \
        acc1 = __builtin_amdgcn_mfma_scale_f32_32x32x64_f8f6f4(             \
            aB1, bk1, acc1, 0, 0, 0, SCALE1, 0, SCALE1);                    \
        /* C/D: col=lane&31, row r2=(reg&3)+8*(reg>>2)+4*h; acc0: m=r2     \
           (all 16 valid); acc1: m=32+r2 -> regs 0..7, +reg8 iff h==0 */   \
        float t0[8];                                                        \
        _Pragma("unroll")                                                   \
        for (int k = 0; k < 8; ++k) t0[k] = fmaxf(acc0[2*k], acc0[2*k+1]);  \
        float t1[4];                                                        \
        _Pragma("unroll")                                                   \
        for (int k = 0; k < 4; ++k) t1[k] = fmaxf(t0[2*k], t0[2*k+1]);      \
        float a0m = fmaxf(fmaxf(t1[0], t1[1]), fmaxf(t1[2], t1[3]));        \
        float u0[4];                                                        \
        _Pragma("unroll")                                                   \
        for (int k = 0; k < 4; ++k) u0[k] = fmaxf(acc1[2*k], acc1[2*k+1]);  \
        float a1m = fmaxf(fmaxf(u0[0], u0[1]), fmaxf(u0[2], u0[3]));        \
        float ex  = (h == 0) ? acc1[8] : NEG_INF;                           \
        float cm  = fmaxf(fmaxf(a0m, a1m), ex);                             \
        cm = fmaxf(cm, __shfl_xor(cm, 32));        /* merge h-halves */     \
        if (h == 0) colmax[wave][t][ml] = cm;                               \
    }

    #pragma unroll 1
    for (int r = 0; r < 2; ++r) {
        {
            const unsigned char* src = csrc + r * 32768;
            #pragma unroll
            for (int it = 0; it < 8; ++it)
                GLDS(src + it * 4096 + tid * 16, bstage + it * 4096 + tid * 16);
        }
        asm volatile("s_waitcnt vmcnt(0)" ::: "memory");
        __builtin_amdgcn_sched_barrier(0);
        __syncthreads();

        #pragma unroll
        for (int ts = 0; ts < 8; ++ts) {
            const int t = r * 8 + ts;
            union { int4 q[2]; v8i v; } b0, b1;
            const unsigned char* base = bstage + ts * 4096 + lane * 16;
            b0.q[0] = *(const int4*)(base);               // k0 lo
            b0.q[1] = *(const int4*)(base + 1024);        // k0 hi
            b1.q[0] = *(const int4*)(base + 2048);        // k1 lo
            b1.q[1] = *(const int4*)(base + 3072);        // k1 hi
            COMPUTE(b0.v, b1.v, t)
        }
        __syncthreads();   // all waves done with bstage before restage
    }

    // ---- epilogue: sum 32 cols per text; write both mirrors ----
    {
        const float scale = expf(nlt[0]);
        const int t = lane & 15;             // text within chunk
        const int q = lane >> 4;             // col octet 0..3
        const float* row = &colmax[wave][t][q * 8];
        float4 a0 = *(const float4*)(row + 0);
        float4 a1 = *(const float4*)(row + 4);
        float s = ((a0.x + a0.y) + (a0.z + a0.w))
                + ((a1.x + a1.y) + (a1.z + a1.w));
        s += __shfl_xor(s, 16);
        s += __shfl_xor(s, 32);              // all 32 cols
        if (q == 0) {
            int tg = tb * 16 + t;
            float v = s * scale / (float)tlen[tg];
            out[im * NT + tg] = v;              // logits_per_image[i,t]
            out[NI * NT + tg * NI + im] = v;    // logits_per_text[t,i]
        }
    }
}

extern "C" void kernel_launch(void* const* d_in, const int* in_sizes, int n_in,
                              void* d_out, int out_size, void* d_ws, size_t ws_size,
                              hipStream_t stream)
{
    const float* img  = (const float*)d_in[0];
    const float* txt  = (const float*)d_in[1];
    const int*   tlen = (const int*)d_in[2];
    const float* nlt  = (const float*)d_in[3];
    float* out = (float*)d_out;

    unsigned char* wsA = (unsigned char*)d_ws;               // 2 MB
    unsigned char* wsB = wsA + (size_t)2 * 1024 * 1024;      // 1 MB

    prep_kernel<<<dim3(512), dim3(256), 0, stream>>>(img, txt, wsA, wsB);
    clip_match_kernel<<<dim3(1024), dim3(256), 0, stream>>>(wsA, wsB, tlen, nlt, out);
}

// Round 29
// 27.633 us; speedup vs baseline: 3.2709x; 1.0497x over previous
//
#include <hip/hip_runtime.h>

typedef int   v8i    __attribute__((ext_vector_type(8)));
typedef float f32x16 __attribute__((ext_vector_type(16)));

#define NI 256
#define NT 256
#define NL 32
#define NE 128
#define HW 49
#define NEG_INF (-3.0e38f)
#define SCALE1 0x7F7F7F7F   // e8m0 = 127 -> x1.0, all blocks

// ws layout (fp8 e4m3, 32x32x64 fragment-linear), validated R15-R24:
//  wsA: frag gw=(i*2+mt)*2+ks; lane l holds 32B at gw*2048 + l*32
//       byte j = img[i, e=ks*64+(l>>5)*32+j, hw=min(mt*32+(l&31),48)]  (2 MB)
//  wsB (SPLIT-16B): frag gw=t*2+ks; lane l bytes 0-15 at gw*2048+l*16,
//       bytes 16-31 at gw*2048+1024+l*16
//       byte j = txt[t, l&31, e=ks*64+(l>>5)*32+j]                     (1 MB)
//  A and B use the SAME k<->(lane,byte) map -> k-permutation cancels.

__device__ __forceinline__ unsigned char f32_to_e4m3(float f)
{
    unsigned fb = __float_as_uint(f);
    unsigned s  = (fb >> 24) & 0x80;
    int      e  = (int)((fb >> 23) & 0xFF);
    unsigned m  = fb & 0x7FFFFF;
    int ne = e - 120;
    if (ne <= 0)  return (unsigned char)s;
    if (ne > 15) { ne = 15; m = 0x600000; }
    unsigned base = ((unsigned)ne << 3) | (m >> 20);
    unsigned rem  = m & 0xFFFFF;
    if (rem > 0x80000 || (rem == 0x80000 && (base & 1))) base++;   // RNE
    if (base > 0x7E) base = 0x7E;
    return (unsigned char)(s | base);
}

// ---------- pre-kernel: whole-chip spread (1280 blocks), R24 exact ----------
__global__ __launch_bounds__(256, 4)
void prep_kernel(const float* __restrict__ img,
                 const float* __restrict__ txt,
                 unsigned char* __restrict__ wsA,
                 unsigned char* __restrict__ wsB)
{
    const int tid  = threadIdx.x;
    const int wave = tid >> 6, lane = tid & 63;
    const int ml   = lane & 31, h = lane >> 5;
    const int bid  = blockIdx.x;
    if (bid < 1024) {                       // A-part: one frag-group per block
        int gw = bid;                       // (i, mt, ks)
        int i  = gw >> 2, mt = (gw >> 1) & 1, ks = gw & 1;
        int m  = mt * 32 + ml; if (m > HW - 1) m = HW - 1;
        int e0 = ks * 64 + h * 32 + wave * 8;     // this wave's 8-e slice
        const float* p = img + ((size_t)i * NE + e0) * HW + m;
        union { unsigned char b[8]; int2 v; } u;
        #pragma unroll
        for (int j = 0; j < 8; ++j) u.b[j] = f32_to_e4m3(p[j * HW]);
        *(int2*)(wsA + (size_t)gw * 2048 + lane * 32 + wave * 8) = u.v;
    } else {                                // B-part: 2 frag-groups per block
        int bb = bid - 1024;                // 0..255
        int gw = bb * 2 + (wave >> 1);      // (t, ks)
        int eh = wave & 1;                  // which 16B half of the lane's 32B
        int t  = gw >> 1, ks = gw & 1;
        int e0 = ks * 64 + h * 32 + eh * 16;
        const float* p = txt + ((size_t)t * NL + ml) * NE + e0;
        union { unsigned char b[16]; int4 v; } u;
        #pragma unroll
        for (int q = 0; q < 4; ++q) {
            float4 f = *(const float4*)(p + q * 4);
            u.b[q*4+0] = f32_to_e4m3(f.x); u.b[q*4+1] = f32_to_e4m3(f.y);
            u.b[q*4+2] = f32_to_e4m3(f.z); u.b[q*4+3] = f32_to_e4m3(f.w);
        }
        *(int4*)(wsB + (size_t)gw * 2048 + eh * 1024 + lane * 16) = u.v;
    }
}

#define GLDS(gp, lp) __builtin_amdgcn_global_load_lds(                     \
        (const __attribute__((address_space(1))) void*)(gp),               \
        (__attribute__((address_space(3))) void*)(lp), 16, 0, 0)

// ---------- main kernel: DOUBLE-BUFFERED B staging ----------
// Grid 1024 = 64 ig x 16 tb, 4 blocks/CU (LDS 40960 exactly). 4 rounds of
// 4 texts; buf[c^1]'s loads are issued a full round early, so the per-round
// wait (counted vmcnt(4), own-wave) is ~free; the two exposed vmcnt(0)
// drains of R24 disappear. Compute per text unchanged (R15/R24 verified).
__global__ __launch_bounds__(256, 4)
void clip_match_kernel(const unsigned char* __restrict__ wsA,
                       const unsigned char* __restrict__ wsB,
                       const int* __restrict__ tlen,
                       const float* __restrict__ nlt,
                       float* __restrict__ out)
{
    const int tid  = threadIdx.x;
    const int wave = tid >> 6, lane = tid & 63;
    const int ml   = lane & 31, h = lane >> 5;
    const int tb   = blockIdx.x & 15;    // text chunk (16 texts)
    const int ig   = blockIdx.x >> 4;    // image group (4 images)
    const int im   = ig * 4 + wave;      // this wave's image

    __shared__ __align__(16) unsigned char bstage[2][16384];  // 2 x 4 texts
    __shared__ __align__(16) float colmax[4][16][32];         // 8 KB
    // total LDS = 40960 B exactly -> 4 blocks/CU

    const unsigned char* pa = wsA + (size_t)im * 8192 + lane * 32;
    v8i aA0 = *(const v8i*)(pa);            // mt0 ks0
    v8i aA1 = *(const v8i*)(pa + 2048);     // mt0 ks1
    v8i aB0 = *(const v8i*)(pa + 4096);     // mt1 ks0
    v8i aB1 = *(const v8i*)(pa + 6144);     // mt1 ks1

    const unsigned char* csrc = wsB + (size_t)tb * 16 * 4096;   // chunk base

    // stage one 16KB round (4 texts): 4 x GLDS per thread
#define STAGE(rr, buf)                                                      \
    {                                                                       \
        const unsigned char* _s = csrc + (rr) * 16384;                      \
        _Pragma("unroll")                                                   \
        for (int q = 0; q < 4; ++q)                                         \
            GLDS(_s + q * 4096 + tid * 16, bstage[buf] + q * 4096 + tid * 16); \
    }

#define COMPUTE(bk0, bk1, t)                                                \
    {                                                                       \
        f32x16 acc0 = __builtin_amdgcn_mfma_scale_f32_32x32x64_f8f6f4(      \
            aA0, bk0, (f32x16)(0.f), 0, 0, 0, SCALE1, 0, SCALE1);           \
        acc0 = __builtin_amdgcn_mfma_scale_f32_32x32x64_f8f6f4(             \
            aA1, bk1, acc0, 0, 0, 0, SCALE1, 0, SCALE1);                    \
        f32x16 acc1 = __builtin_amdgcn_mfma_scale_f32_32x32x64_f8f6f4(      \
            aB0, bk0, (f32x16)(0.f), 0, 0, 0, SCALE1, 0, SCALE1);           \
        acc1 = __builtin_amdgcn_mfma_scale_f32_32x32x64_f8f6f4(             \
            aB1, bk1, acc1, 0, 0, 0, SCALE1, 0, SCALE1);                    \
        /* C/D: col=lane&31, row r2=(reg&3)+8*(reg>>2)+4*h; acc0: m=r2     \
           (all 16 valid); acc1: m=32+r2 -> regs 0..7, +reg8 iff h==0 */   \
        float t0[8];                                                        \
        _Pragma("unroll")                                                   \
        for (int k = 0; k < 8; ++k) t0[k] = fmaxf(acc0[2*k], acc0[2*k+1]);  \
        float t1[4];                                                        \
        _Pragma("unroll")                                                   \
        for (int k = 0; k < 4; ++k) t1[k] = fmaxf(t0[2*k], t0[2*k+1]);      \
        float a0m = fmaxf(fmaxf(t1[0], t1[1]), fmaxf(t1[2], t1[3]));        \
        float u0[4];                                                        \
        _Pragma("unroll")                                                   \
        for (int k = 0; k < 4; ++k) u0[k] = fmaxf(acc1[2*k], acc1[2*k+1]);  \
        float a1m = fmaxf(fmaxf(u0[0], u0[1]), fmaxf(u0[2], u0[3]));        \
        float ex  = (h == 0) ? acc1[8] : NEG_INF;                           \
        float cm  = fmaxf(fmaxf(a0m, a1m), ex);                             \
        cm = fmaxf(cm, __shfl_xor(cm, 32));        /* merge h-halves */     \
        if (h == 0) colmax[wave][t][ml] = cm;                               \
    }

    // prologue: rounds 0,1 in flight (8 loads/thread outstanding)
    STAGE(0, 0)
    STAGE(1, 1)
    asm volatile("s_waitcnt vmcnt(4)" ::: "memory");   // round 0 landed
    __builtin_amdgcn_sched_barrier(0);
    __syncthreads();

    int c = 0;
    #pragma unroll 1
    for (int r = 0; r < 4; ++r) {
        // compute 4 texts from bstage[c]
        #pragma unroll
        for (int ts = 0; ts < 4; ++ts) {
            const int t = r * 4 + ts;
            union { int4 q[2]; v8i v; } b0, b1;
            const unsigned char* base = bstage[c] + ts * 4096 + lane * 16;
            b0.q[0] = *(const int4*)(base);               // k0 lo
            b0.q[1] = *(const int4*)(base + 1024);        // k0 hi
            b1.q[0] = *(const int4*)(base + 2048);        // k1 lo
            b1.q[1] = *(const int4*)(base + 3072);        // k1 hi
            COMPUTE(b0.v, b1.v, t)
        }
        if (r == 3) break;
        __syncthreads();                   // all waves done reading buf c
        if (r < 2) STAGE(r + 2, c)         // refill buf c (round r+2)
        // wait for buf c^1 (issued a full round ago -> ~already landed)
        if (r < 2) { asm volatile("s_waitcnt vmcnt(4)" ::: "memory"); }
        else       { asm volatile("s_waitcnt vmcnt(0)" ::: "memory"); }
        __builtin_amdgcn_sched_barrier(0);
        __syncthreads();                   // all waves' loads for c^1 landed
        c ^= 1;
    }
#undef COMPUTE
#undef STAGE

    // ---- epilogue: sum 32 cols per text; write both mirrors ----
    {
        const float scale = expf(nlt[0]);
        const int t = lane & 15;             // text within chunk
        const int q = lane >> 4;             // col octet 0..3
        const float* row = &colmax[wave][t][q * 8];
        float4 a0 = *(const float4*)(row + 0);
        float4 a1 = *(const float4*)(row + 4);
        float s = ((a0.x + a0.y) + (a0.z + a0.w))
                + ((a1.x + a1.y) + (a1.z + a1.w));
        s += __shfl_xor(s, 16);
        s += __shfl_xor(s, 32);              // all 32 cols
        if (q == 0) {
            int tg = tb * 16 + t;
            float v = s * scale / (float)tlen[tg];
            out[im * NT + tg] = v;              // logits_per_image[i,t]
            out[NI * NT + tg * NI + im] = v;    // logits_per_text[t,i]
        }
    }
}

extern "C" void kernel_launch(void* const* d_in, const int* in_sizes, int n_in,
                              void* d_out, int out_size, void* d_ws, size_t ws_size,
                              hipStream_t stream)
{
    const float* img  = (const float*)d_in[0];
    const float* txt  = (const float*)d_in[1];
    const int*   tlen = (const int*)d_in[2];
    const float* nlt  = (const float*)d_in[3];
    float* out = (float*)d_out;

    unsigned char* wsA = (unsigned char*)d_ws;               // 2 MB
    unsigned char* wsB = wsA + (size_t)2 * 1024 * 1024;      // 1 MB

    prep_kernel<<<dim3(1280), dim3(256), 0, stream>>>(img, txt, wsA, wsB);
    clip_match_kernel<<<dim3(1024), dim3(256), 0, stream>>>(wsA, wsB, tlen, nlt, out);
}